// Round 11
// baseline (500.619 us; speedup 1.0000x reference)
//
#include <hip/hip_runtime.h>

#define NGROUPS 50000
#define NITEMS  100000
#define NNODES  150000
#define NEDGES  2400000
#define DIM     64
#define NCOPY   8   // privatized histogram copies (contention / 8)

// round-to-nearest f32 -> bf16 (as raw ushort)
__device__ __forceinline__ ushort f2bf(float f) {
    unsigned u = __float_as_uint(f);
    u += 0x7FFF + ((u >> 16) & 1);
    return (ushort)(u >> 16);
}
__device__ __forceinline__ float bf2f(ushort h) {
    return __uint_as_float((unsigned)h << 16);
}

// ============================ CSR-gather path ==============================

// FUSED: (a) f32 groups||items -> bf16 table x0b (streaming prologue),
//        (b) 8-way privatized row histogram + intra-row-per-copy rank.
// Copy c = tid&7: same row from different threads spreads over 8 cache lines,
// cutting per-line atomic serialization 8x (R10 showed contention-bound).
__global__ __launch_bounds__(256) void k_conv_hist(const float4* __restrict__ g,
                                                   const float4* __restrict__ it,
                                                   ushort4* __restrict__ xb,
                                                   const int4* __restrict__ rows4,
                                                   int* __restrict__ cnt8,
                                                   int4* __restrict__ rank4) {
    int tid = blockIdx.x * blockDim.x + threadIdx.x;
    int s   = gridDim.x * blockDim.x;

    const int n1 = NGROUPS * DIM / 4;
    const int nc = NNODES * DIM / 4;
    for (int i = tid; i < nc; i += s) {
        float4 v = (i < n1) ? g[i] : it[i - n1];
        ushort4 h;
        h.x = f2bf(v.x); h.y = f2bf(v.y); h.z = f2bf(v.z); h.w = f2bf(v.w);
        xb[i] = h;
    }

    int* cop = cnt8 + (size_t)(tid & (NCOPY - 1)) * NNODES;
    const int n4 = NEDGES / 4;
    for (int i = tid; i < n4; i += s) {
        int4 r = rows4[i];
        int4 k;
        k.x = atomicAdd(&cop[r.x], 1);
        k.y = atomicAdd(&cop[r.y], 1);
        k.z = atomicAdd(&cop[r.z], 1);
        k.w = atomicAdd(&cop[r.w], 1);
        rank4[i] = k;
    }
}

// per-row exclusive scan across the 8 copies (in place) + row total -> cnt
__global__ __launch_bounds__(256) void k_cscan(int* __restrict__ cnt8,
                                               int* __restrict__ cnt) {
    int r = blockIdx.x * blockDim.x + threadIdx.x;
    if (r >= NNODES) return;
    int run = 0;
    #pragma unroll
    for (int c = 0; c < NCOPY; ++c) {
        int v = cnt8[(size_t)c * NNODES + r];
        cnt8[(size_t)c * NNODES + r] = run;
        run += v;
    }
    cnt[r] = run;
}

__global__ __launch_bounds__(256) void k_bsum(const int* __restrict__ cnt,
                                              int* __restrict__ bsum) {
    __shared__ int s[256];
    int t = threadIdx.x;
    int i = blockIdx.x * 256 + t;
    s[t] = (i < NNODES) ? cnt[i] : 0;
    __syncthreads();
    for (int off = 128; off > 0; off >>= 1) {
        if (t < off) s[t] += s[t + off];
        __syncthreads();
    }
    if (t == 0) bsum[blockIdx.x] = s[0];
}

__global__ __launch_bounds__(1024) void k_scanb(const int* __restrict__ bsum,
                                                int* __restrict__ boff, int nb) {
    __shared__ int s[1024];
    int t = threadIdx.x;
    int v = (t < nb) ? bsum[t] : 0;
    s[t] = v;
    __syncthreads();
    for (int off = 1; off < 1024; off <<= 1) {
        int u = (t >= off) ? s[t - off] : 0;
        __syncthreads();
        s[t] += u;
        __syncthreads();
    }
    if (t < nb) boff[t] = s[t] - v;   // exclusive
}

__global__ __launch_bounds__(256) void k_rowptr(const int* __restrict__ cnt,
                                                const int* __restrict__ boff,
                                                int* __restrict__ rowptr) {
    __shared__ int s[256];
    int t = threadIdx.x;
    int i = blockIdx.x * 256 + t;
    int c = (i < NNODES) ? cnt[i] : 0;
    s[t] = c;
    __syncthreads();
    for (int off = 1; off < 256; off <<= 1) {
        int u = (t >= off) ? s[t - off] : 0;
        __syncthreads();
        s[t] += u;
        __syncthreads();
    }
    int base = boff[blockIdx.x];
    int excl = base + s[t] - c;
    if (i < NNODES) {
        rowptr[i] = excl;
        if (i == NNODES - 1) rowptr[NNODES] = excl + c;   // == NEDGES
    }
}

// atomic-free permute: pos = rowptr[r] + copyoff[c][r] + rank; 4 edges/thread.
// MUST use the same grid + copy formula (tid&7) as k_conv_hist.
__global__ __launch_bounds__(256) void k_scatter(const int4* __restrict__ rows4,
                                                 const int4* __restrict__ cols4,
                                                 const float4* __restrict__ vals4,
                                                 const int4* __restrict__ rank4,
                                                 const int* __restrict__ rowptr,
                                                 const int* __restrict__ cnt8,
                                                 int2* __restrict__ scv) {
    int tid = blockIdx.x * blockDim.x + threadIdx.x;
    int s   = gridDim.x * blockDim.x;
    const int* cop = cnt8 + (size_t)(tid & (NCOPY - 1)) * NNODES;
    const int n4 = NEDGES / 4;
    for (int i = tid; i < n4; i += s) {
        int4   r = rows4[i];
        int4   c = cols4[i];
        float4 v = vals4[i];
        int4   k = rank4[i];
        scv[rowptr[r.x] + cop[r.x] + k.x] = make_int2(c.x, __float_as_int(v.x));
        scv[rowptr[r.y] + cop[r.y] + k.y] = make_int2(c.y, __float_as_int(v.y));
        scv[rowptr[r.z] + cop[r.z] + k.z] = make_int2(c.z, __float_as_int(v.z));
        scv[rowptr[r.w] + cop[r.w] + k.w] = make_int2(c.w, __float_as_int(v.w));
    }
}

// ---- gather SpMM over bf16 x-table: one wave per row; 4 lane-quarters each
// own an edge; 16 lanes * ushort4 = 128B = ONE cache line per edge gather.
// LAYER 1: gather x0b, write y=x1b, out[r] = acc (f32, r<NGROUPS)
// LAYER 2: gather x1b, write y=x2b, out[r] += acc
// LAYER 3: rows [0,NGROUPS) only; gather x2b; out = (out+groups+acc)*0.25
template <int LAYER>
__global__ __launch_bounds__(256) void k_spmm_csr(const int* __restrict__ rowptr,
                                                  const int2* __restrict__ scv,
                                                  const ushort* __restrict__ xsrc,
                                                  const float4* __restrict__ groups4,
                                                  ushort* __restrict__ y,
                                                  float4* __restrict__ out4) {
    int r    = blockIdx.x * 4 + (threadIdx.x >> 6);
    int lane = threadIdx.x & 63;
    int q    = lane >> 4;      // quarter 0..3 — which edge of a group of 4
    int sl   = lane & 15;      // 0..15 — ushort4 slot within the row
    int beg = rowptr[r], end = rowptr[r + 1];

    float4 acc = make_float4(0.f, 0.f, 0.f, 0.f);
    for (int j = beg + q; j < end; j += 4) {
        int2  cv = scv[j];
        int   c  = cv.x;
        float v  = __int_as_float(cv.y);
        ushort4 h = ((const ushort4*)(xsrc + (size_t)c * DIM))[sl];
        acc.x = fmaf(v, bf2f(h.x), acc.x);
        acc.y = fmaf(v, bf2f(h.y), acc.y);
        acc.z = fmaf(v, bf2f(h.z), acc.z);
        acc.w = fmaf(v, bf2f(h.w), acc.w);
    }
    // combine the 4 quarters: all lanes end up holding the full row sum
    acc.x += __shfl_xor(acc.x, 16, 64);
    acc.y += __shfl_xor(acc.y, 16, 64);
    acc.z += __shfl_xor(acc.z, 16, 64);
    acc.w += __shfl_xor(acc.w, 16, 64);
    acc.x += __shfl_xor(acc.x, 32, 64);
    acc.y += __shfl_xor(acc.y, 32, 64);
    acc.z += __shfl_xor(acc.z, 32, 64);
    acc.w += __shfl_xor(acc.w, 32, 64);

    if (lane < 16) {
        size_t o = (size_t)r * 16 + sl;     // float4 / ushort4 row slot
        if (LAYER != 3) {
            ushort4 h;
            h.x = f2bf(acc.x); h.y = f2bf(acc.y);
            h.z = f2bf(acc.z); h.w = f2bf(acc.w);
            ((ushort4*)(y + (size_t)r * DIM))[sl] = h;
        }
        if (LAYER == 1) {
            if (r < NGROUPS) out4[o] = acc;
        } else if (LAYER == 2) {
            if (r < NGROUPS) {
                float4 a = out4[o];
                a.x += acc.x; a.y += acc.y; a.z += acc.z; a.w += acc.w;
                out4[o] = a;
            }
        } else {
            float4 a = out4[o];
            float4 g = groups4[o];
            a.x = (a.x + g.x + acc.x) * 0.25f;
            a.y = (a.y + g.y + acc.y) * 0.25f;
            a.z = (a.z + g.z + acc.z) * 0.25f;
            a.w = (a.w + g.w + acc.w) * 0.25f;
            out4[o] = a;
        }
    }
}

// ====================== fallback path (atomic scatter) ======================

__global__ __launch_bounds__(256) void k_zero(float4* __restrict__ p, int n4) {
    int i = blockIdx.x * blockDim.x + threadIdx.x;
    int s = gridDim.x * blockDim.x;
    float4 z = make_float4(0.f, 0.f, 0.f, 0.f);
    for (; i < n4; i += s) p[i] = z;
}

__global__ __launch_bounds__(256) void k_concat(const float4* __restrict__ g,
                                                const float4* __restrict__ it,
                                                float4* __restrict__ x) {
    const int n1 = NGROUPS * DIM / 4;
    const int n  = NNODES * DIM / 4;
    int i = blockIdx.x * blockDim.x + threadIdx.x;
    int s = gridDim.x * blockDim.x;
    for (; i < n; i += s) x[i] = (i < n1) ? g[i] : it[i - n1];
}

__global__ __launch_bounds__(256) void k_spmm(const int*   __restrict__ rows,
                                              const int*   __restrict__ cols,
                                              const float* __restrict__ vals,
                                              const float* __restrict__ x,
                                              float*       __restrict__ y) {
    int wid  = (blockIdx.x * blockDim.x + threadIdx.x) >> 6;
    int lane = threadIdx.x & 63;
    int nw   = (gridDim.x * blockDim.x) >> 6;
    for (int e = wid; e < NEDGES; e += nw) {
        int   r = rows[e];
        int   c = cols[e];
        float v = vals[e];
        unsafeAtomicAdd(&y[r * DIM + lane], v * x[c * DIM + lane]);
    }
}

__global__ __launch_bounds__(256) void k_accum(const float4* __restrict__ src,
                                               float4* __restrict__ dst, int first) {
    const int n = NGROUPS * DIM / 4;
    int i = blockIdx.x * blockDim.x + threadIdx.x;
    int s = gridDim.x * blockDim.x;
    if (first) { for (; i < n; i += s) dst[i] = src[i]; }
    else {
        for (; i < n; i += s) {
            float4 a = dst[i], b = src[i];
            a.x += b.x; a.y += b.y; a.z += b.z; a.w += b.w;
            dst[i] = a;
        }
    }
}

__global__ __launch_bounds__(256) void k_final(const float4* __restrict__ g,
                                               float4* __restrict__ out) {
    const int n = NGROUPS * DIM / 4;
    int i = blockIdx.x * blockDim.x + threadIdx.x;
    int s = gridDim.x * blockDim.x;
    for (; i < n; i += s) {
        float4 a = out[i], b = g[i];
        out[i] = make_float4((a.x + b.x) * 0.25f, (a.y + b.y) * 0.25f,
                             (a.z + b.z) * 0.25f, (a.w + b.w) * 0.25f);
    }
}

// ===========================================================================

extern "C" void kernel_launch(void* const* d_in, const int* in_sizes, int n_in,
                              void* d_out, int out_size, void* d_ws, size_t ws_size,
                              hipStream_t stream) {
    const float* groups = (const float*)d_in[0];
    const float* items  = (const float*)d_in[1];
    const float* vals   = (const float*)d_in[2];
    const int*   rows   = (const int*)d_in[3];
    const int*   cols   = (const int*)d_in[4];
    float* out = (float*)d_out;

    const int NB = (NNODES + 255) / 256;              // 586 blocks

    // ws layout (float units) — unchanged from R10 (cnt8 aliases x1).
    size_t off = 0;
    float* x1     = (float*)d_ws;               off += (size_t)NNODES * DIM;
    float* x2     = (float*)d_ws + off;         off += (size_t)NNODES * DIM;
    int*   cnt    = (int*)((float*)d_ws + off); off += NNODES;
    int*   rowptr = (int*)((float*)d_ws + off); off += NNODES + 4;
    int*   bsum   = (int*)((float*)d_ws + off); off += 1024;
    int*   boff   = (int*)((float*)d_ws + off); off += 1024;
    int2*  scv    = (int2*)((float*)d_ws + off); off += (size_t)NEDGES * 2; // 8B-aligned
    float* x0     = (float*)d_ws + off;         off += (size_t)NNODES * DIM / 2; // bf16 table
    size_t needed = off * sizeof(float);

    ushort* x0b = (ushort*)x0;
    ushort* x1b = (ushort*)x1;
    ushort* x2b = (ushort*)x2;
    // Aliases (no ws growth):
    //  - cnt8[8][NNODES] (4.8 MB) lives in the x1 region; dead before spmm<1>
    //    writes x1b.
    //  - rank[NEDGES] lives in the x2 region; dead before spmm<2> writes x2b.
    int* cnt8 = (int*)x1;
    int* rank = (int*)x2;

    dim3 blk(256);

    if (ws_size >= needed) {
        // ---- CSR build (privatized hist + atomic-free permute) ----
        hipMemsetAsync(cnt8, 0, (size_t)NCOPY * NNODES * sizeof(int), stream);
        k_conv_hist<<<2048, blk, 0, stream>>>((const float4*)groups, (const float4*)items,
                                              (ushort4*)x0b, (const int4*)rows,
                                              cnt8, (int4*)rank);
        k_cscan<<<NB, blk, 0, stream>>>(cnt8, cnt);
        k_bsum<<<NB, blk, 0, stream>>>(cnt, bsum);
        k_scanb<<<1, dim3(1024), 0, stream>>>(bsum, boff, NB);
        k_rowptr<<<NB, blk, 0, stream>>>(cnt, boff, rowptr);
        k_scatter<<<2048, blk, 0, stream>>>((const int4*)rows, (const int4*)cols,
                                            (const float4*)vals, (const int4*)rank,
                                            rowptr, cnt8, scv);

        // ---- 3 gather layers (bf16 gathers), fused output accumulation ----
        k_spmm_csr<1><<<NNODES / 4, blk, 0, stream>>>(rowptr, scv, x0b,
                                                      (const float4*)groups, x1b,
                                                      (float4*)out);
        k_spmm_csr<2><<<NNODES / 4, blk, 0, stream>>>(rowptr, scv, x1b,
                                                      (const float4*)groups, x2b,
                                                      (float4*)out);
        k_spmm_csr<3><<<NGROUPS / 4, blk, 0, stream>>>(rowptr, scv, x2b,
                                                       (const float4*)groups, nullptr,
                                                       (float4*)out);
    } else {
        // ---- fallback: proven atomic-scatter path (f32) ----
        float* xA = x1;
        float* xB = x2;
        k_concat<<<2048, blk, 0, stream>>>((const float4*)groups, (const float4*)items,
                                           (float4*)xA);
        for (int l = 0; l < 3; ++l) {
            k_zero<<<2048, blk, 0, stream>>>((float4*)xB, NNODES * DIM / 4);
            k_spmm<<<4096, blk, 0, stream>>>(rows, cols, vals, xA, xB);
            k_accum<<<512, blk, 0, stream>>>((const float4*)xB, (float4*)out, l == 0);
            float* t = xA; xA = xB; xB = t;
        }
        k_final<<<512, blk, 0, stream>>>((const float4*)groups, (float4*)out);
    }
}

// Round 12
// 469.684 us; speedup vs baseline: 1.0659x; 1.0659x over previous
//
#include <hip/hip_runtime.h>

#define NGROUPS 50000
#define NITEMS  100000
#define NNODES  150000
#define NEDGES  2400000
#define DIM     64
#define NCOPY   8   // privatized histogram copies

// round-to-nearest f32 -> bf16 (as raw ushort)
__device__ __forceinline__ ushort f2bf(float f) {
    unsigned u = __float_as_uint(f);
    u += 0x7FFF + ((u >> 16) & 1);
    return (ushort)(u >> 16);
}
__device__ __forceinline__ float bf2f(ushort h) {
    return __uint_as_float((unsigned)h << 16);
}

// ============================ CSR-gather path ==============================

// f32 groups||items -> bf16 table x0b (separate: fusion with hist measured
// slower in R10; streaming kernel runs at BW)
__global__ __launch_bounds__(256) void k_tobf16(const float4* __restrict__ g,
                                                const float4* __restrict__ it,
                                                ushort4* __restrict__ xb) {
    const int n1 = NGROUPS * DIM / 4;
    const int n  = NNODES * DIM / 4;
    int i = blockIdx.x * blockDim.x + threadIdx.x;
    int s = gridDim.x * blockDim.x;
    for (; i < n; i += s) {
        float4 v = (i < n1) ? g[i] : it[i - n1];
        ushort4 h;
        h.x = f2bf(v.x); h.y = f2bf(v.y); h.z = f2bf(v.z); h.w = f2bf(v.w);
        xb[i] = h;
    }
}

// 8-way privatized row histogram + intra-row-per-copy rank (counting sort).
// Run at 1024 blocks: measured-best for the atomic-rtn issue ceiling (R8 vs
// R10/R11 — over-subscription queues atomics and runs slower).
__global__ __launch_bounds__(256) void k_hist(const int4* __restrict__ rows4,
                                              int* __restrict__ cnt8,
                                              int4* __restrict__ rank4) {
    int tid = blockIdx.x * blockDim.x + threadIdx.x;
    int s   = gridDim.x * blockDim.x;
    int* cop = cnt8 + (size_t)(tid & (NCOPY - 1)) * NNODES;
    const int n4 = NEDGES / 4;
    for (int i = tid; i < n4; i += s) {
        int4 r = rows4[i];
        int4 k;
        k.x = atomicAdd(&cop[r.x], 1);
        k.y = atomicAdd(&cop[r.y], 1);
        k.z = atomicAdd(&cop[r.z], 1);
        k.w = atomicAdd(&cop[r.w], 1);
        rank4[i] = k;
    }
}

// per-row exclusive scan across the 8 copies (in place) + row total -> cnt
__global__ __launch_bounds__(256) void k_cscan(int* __restrict__ cnt8,
                                               int* __restrict__ cnt) {
    int r = blockIdx.x * blockDim.x + threadIdx.x;
    if (r >= NNODES) return;
    int run = 0;
    #pragma unroll
    for (int c = 0; c < NCOPY; ++c) {
        int v = cnt8[(size_t)c * NNODES + r];
        cnt8[(size_t)c * NNODES + r] = run;
        run += v;
    }
    cnt[r] = run;
}

__global__ __launch_bounds__(256) void k_bsum(const int* __restrict__ cnt,
                                              int* __restrict__ bsum) {
    __shared__ int s[256];
    int t = threadIdx.x;
    int i = blockIdx.x * 256 + t;
    s[t] = (i < NNODES) ? cnt[i] : 0;
    __syncthreads();
    for (int off = 128; off > 0; off >>= 1) {
        if (t < off) s[t] += s[t + off];
        __syncthreads();
    }
    if (t == 0) bsum[blockIdx.x] = s[0];
}

__global__ __launch_bounds__(1024) void k_scanb(const int* __restrict__ bsum,
                                                int* __restrict__ boff, int nb) {
    __shared__ int s[1024];
    int t = threadIdx.x;
    int v = (t < nb) ? bsum[t] : 0;
    s[t] = v;
    __syncthreads();
    for (int off = 1; off < 1024; off <<= 1) {
        int u = (t >= off) ? s[t - off] : 0;
        __syncthreads();
        s[t] += u;
        __syncthreads();
    }
    if (t < nb) boff[t] = s[t] - v;   // exclusive
}

__global__ __launch_bounds__(256) void k_rowptr(const int* __restrict__ cnt,
                                                const int* __restrict__ boff,
                                                int* __restrict__ rowptr) {
    __shared__ int s[256];
    int t = threadIdx.x;
    int i = blockIdx.x * 256 + t;
    int c = (i < NNODES) ? cnt[i] : 0;
    s[t] = c;
    __syncthreads();
    for (int off = 1; off < 256; off <<= 1) {
        int u = (t >= off) ? s[t - off] : 0;
        __syncthreads();
        s[t] += u;
        __syncthreads();
    }
    int base = boff[blockIdx.x];
    int excl = base + s[t] - c;
    if (i < NNODES) {
        rowptr[i] = excl;
        if (i == NNODES - 1) rowptr[NNODES] = excl + c;   // == NEDGES
    }
}

// atomic-free permute: pos = rowptr[r] + copyoff[c][r] + rank; 4 edges/thread.
// MUST use the same grid + copy formula (tid&7) as k_hist.
__global__ __launch_bounds__(256) void k_scatter(const int4* __restrict__ rows4,
                                                 const int4* __restrict__ cols4,
                                                 const float4* __restrict__ vals4,
                                                 const int4* __restrict__ rank4,
                                                 const int* __restrict__ rowptr,
                                                 const int* __restrict__ cnt8,
                                                 int2* __restrict__ scv) {
    int tid = blockIdx.x * blockDim.x + threadIdx.x;
    int s   = gridDim.x * blockDim.x;
    const int* cop = cnt8 + (size_t)(tid & (NCOPY - 1)) * NNODES;
    const int n4 = NEDGES / 4;
    for (int i = tid; i < n4; i += s) {
        int4   r = rows4[i];
        int4   c = cols4[i];
        float4 v = vals4[i];
        int4   k = rank4[i];
        scv[rowptr[r.x] + cop[r.x] + k.x] = make_int2(c.x, __float_as_int(v.x));
        scv[rowptr[r.y] + cop[r.y] + k.y] = make_int2(c.y, __float_as_int(v.y));
        scv[rowptr[r.z] + cop[r.z] + k.z] = make_int2(c.z, __float_as_int(v.z));
        scv[rowptr[r.w] + cop[r.w] + k.w] = make_int2(c.w, __float_as_int(v.w));
    }
}

// ---- gather SpMM over bf16 x-table: one wave per row; 4 lane-quarters each
// own an edge; 16 lanes * ushort4 = 128B = ONE cache line per edge gather.
// 2-edge manual unroll per quarter -> 8 gathers in flight per wave (the loop
// is data-dependent; hipcc won't unroll it itself).
template <int LAYER>
__global__ __launch_bounds__(256) void k_spmm_csr(const int* __restrict__ rowptr,
                                                  const int2* __restrict__ scv,
                                                  const ushort* __restrict__ xsrc,
                                                  const float4* __restrict__ groups4,
                                                  ushort* __restrict__ y,
                                                  float4* __restrict__ out4) {
    int r    = blockIdx.x * 4 + (threadIdx.x >> 6);
    int lane = threadIdx.x & 63;
    int q    = lane >> 4;      // quarter 0..3 — which edge of a group of 4
    int sl   = lane & 15;      // 0..15 — ushort4 slot within the row
    int beg = rowptr[r], end = rowptr[r + 1];

    float4 acc = make_float4(0.f, 0.f, 0.f, 0.f);
    int j = beg + q;
    for (; j + 4 < end; j += 8) {
        int2  cv0 = scv[j];
        int2  cv1 = scv[j + 4];
        float v0  = __int_as_float(cv0.y);
        float v1  = __int_as_float(cv1.y);
        ushort4 h0 = ((const ushort4*)(xsrc + (size_t)cv0.x * DIM))[sl];
        ushort4 h1 = ((const ushort4*)(xsrc + (size_t)cv1.x * DIM))[sl];
        acc.x = fmaf(v0, bf2f(h0.x), acc.x);
        acc.y = fmaf(v0, bf2f(h0.y), acc.y);
        acc.z = fmaf(v0, bf2f(h0.z), acc.z);
        acc.w = fmaf(v0, bf2f(h0.w), acc.w);
        acc.x = fmaf(v1, bf2f(h1.x), acc.x);
        acc.y = fmaf(v1, bf2f(h1.y), acc.y);
        acc.z = fmaf(v1, bf2f(h1.z), acc.z);
        acc.w = fmaf(v1, bf2f(h1.w), acc.w);
    }
    if (j < end) {
        int2  cv = scv[j];
        float v  = __int_as_float(cv.y);
        ushort4 h = ((const ushort4*)(xsrc + (size_t)cv.x * DIM))[sl];
        acc.x = fmaf(v, bf2f(h.x), acc.x);
        acc.y = fmaf(v, bf2f(h.y), acc.y);
        acc.z = fmaf(v, bf2f(h.z), acc.z);
        acc.w = fmaf(v, bf2f(h.w), acc.w);
    }
    // combine the 4 quarters: all lanes end up holding the full row sum
    acc.x += __shfl_xor(acc.x, 16, 64);
    acc.y += __shfl_xor(acc.y, 16, 64);
    acc.z += __shfl_xor(acc.z, 16, 64);
    acc.w += __shfl_xor(acc.w, 16, 64);
    acc.x += __shfl_xor(acc.x, 32, 64);
    acc.y += __shfl_xor(acc.y, 32, 64);
    acc.z += __shfl_xor(acc.z, 32, 64);
    acc.w += __shfl_xor(acc.w, 32, 64);

    if (lane < 16) {
        size_t o = (size_t)r * 16 + sl;     // float4 / ushort4 row slot
        if (LAYER != 3) {
            ushort4 h;
            h.x = f2bf(acc.x); h.y = f2bf(acc.y);
            h.z = f2bf(acc.z); h.w = f2bf(acc.w);
            ((ushort4*)(y + (size_t)r * DIM))[sl] = h;
        }
        if (LAYER == 1) {
            if (r < NGROUPS) out4[o] = acc;
        } else if (LAYER == 2) {
            if (r < NGROUPS) {
                float4 a = out4[o];
                a.x += acc.x; a.y += acc.y; a.z += acc.z; a.w += acc.w;
                out4[o] = a;
            }
        } else {
            float4 a = out4[o];
            float4 g = groups4[o];
            a.x = (a.x + g.x + acc.x) * 0.25f;
            a.y = (a.y + g.y + acc.y) * 0.25f;
            a.z = (a.z + g.z + acc.z) * 0.25f;
            a.w = (a.w + g.w + acc.w) * 0.25f;
            out4[o] = a;
        }
    }
}

// ====================== fallback path (atomic scatter) ======================

__global__ __launch_bounds__(256) void k_zero(float4* __restrict__ p, int n4) {
    int i = blockIdx.x * blockDim.x + threadIdx.x;
    int s = gridDim.x * blockDim.x;
    float4 z = make_float4(0.f, 0.f, 0.f, 0.f);
    for (; i < n4; i += s) p[i] = z;
}

__global__ __launch_bounds__(256) void k_concat(const float4* __restrict__ g,
                                                const float4* __restrict__ it,
                                                float4* __restrict__ x) {
    const int n1 = NGROUPS * DIM / 4;
    const int n  = NNODES * DIM / 4;
    int i = blockIdx.x * blockDim.x + threadIdx.x;
    int s = gridDim.x * blockDim.x;
    for (; i < n; i += s) x[i] = (i < n1) ? g[i] : it[i - n1];
}

__global__ __launch_bounds__(256) void k_spmm(const int*   __restrict__ rows,
                                              const int*   __restrict__ cols,
                                              const float* __restrict__ vals,
                                              const float* __restrict__ x,
                                              float*       __restrict__ y) {
    int wid  = (blockIdx.x * blockDim.x + threadIdx.x) >> 6;
    int lane = threadIdx.x & 63;
    int nw   = (gridDim.x * blockDim.x) >> 6;
    for (int e = wid; e < NEDGES; e += nw) {
        int   r = rows[e];
        int   c = cols[e];
        float v = vals[e];
        unsafeAtomicAdd(&y[r * DIM + lane], v * x[c * DIM + lane]);
    }
}

__global__ __launch_bounds__(256) void k_accum(const float4* __restrict__ src,
                                               float4* __restrict__ dst, int first) {
    const int n = NGROUPS * DIM / 4;
    int i = blockIdx.x * blockDim.x + threadIdx.x;
    int s = gridDim.x * blockDim.x;
    if (first) { for (; i < n; i += s) dst[i] = src[i]; }
    else {
        for (; i < n; i += s) {
            float4 a = dst[i], b = src[i];
            a.x += b.x; a.y += b.y; a.z += b.z; a.w += b.w;
            dst[i] = a;
        }
    }
}

__global__ __launch_bounds__(256) void k_final(const float4* __restrict__ g,
                                               float4* __restrict__ out) {
    const int n = NGROUPS * DIM / 4;
    int i = blockIdx.x * blockDim.x + threadIdx.x;
    int s = gridDim.x * blockDim.x;
    for (; i < n; i += s) {
        float4 a = out[i], b = g[i];
        out[i] = make_float4((a.x + b.x) * 0.25f, (a.y + b.y) * 0.25f,
                             (a.z + b.z) * 0.25f, (a.w + b.w) * 0.25f);
    }
}

// ===========================================================================

extern "C" void kernel_launch(void* const* d_in, const int* in_sizes, int n_in,
                              void* d_out, int out_size, void* d_ws, size_t ws_size,
                              hipStream_t stream) {
    const float* groups = (const float*)d_in[0];
    const float* items  = (const float*)d_in[1];
    const float* vals   = (const float*)d_in[2];
    const int*   rows   = (const int*)d_in[3];
    const int*   cols   = (const int*)d_in[4];
    float* out = (float*)d_out;

    const int NB = (NNODES + 255) / 256;              // 586 blocks

    // ws layout (float units) — unchanged (cnt8 aliases x1, rank aliases x2).
    size_t off = 0;
    float* x1     = (float*)d_ws;               off += (size_t)NNODES * DIM;
    float* x2     = (float*)d_ws + off;         off += (size_t)NNODES * DIM;
    int*   cnt    = (int*)((float*)d_ws + off); off += NNODES;
    int*   rowptr = (int*)((float*)d_ws + off); off += NNODES + 4;
    int*   bsum   = (int*)((float*)d_ws + off); off += 1024;
    int*   boff   = (int*)((float*)d_ws + off); off += 1024;
    int2*  scv    = (int2*)((float*)d_ws + off); off += (size_t)NEDGES * 2; // 8B-aligned
    float* x0     = (float*)d_ws + off;         off += (size_t)NNODES * DIM / 2; // bf16 table
    size_t needed = off * sizeof(float);

    ushort* x0b = (ushort*)x0;
    ushort* x1b = (ushort*)x1;
    ushort* x2b = (ushort*)x2;
    int* cnt8 = (int*)x1;   // 4.8 MB, dead before spmm<1> writes x1b
    int* rank = (int*)x2;   // 9.6 MB, dead before spmm<2> writes x2b

    dim3 blk(256);

    if (ws_size >= needed) {
        // ---- CSR build (privatized hist @1024 blocks + atomic-free permute) ----
        hipMemsetAsync(cnt8, 0, (size_t)NCOPY * NNODES * sizeof(int), stream);
        k_tobf16<<<1024, blk, 0, stream>>>((const float4*)groups, (const float4*)items,
                                           (ushort4*)x0b);
        // 1024 blocks: measured-best for atomic-rtn throughput (R8 99us vs
        // R10/R11 ~130us at 2048 — over-subscription queues the atomic unit).
        k_hist<<<1024, blk, 0, stream>>>((const int4*)rows, cnt8, (int4*)rank);
        k_cscan<<<NB, blk, 0, stream>>>(cnt8, cnt);
        k_bsum<<<NB, blk, 0, stream>>>(cnt, bsum);
        k_scanb<<<1, dim3(1024), 0, stream>>>(bsum, boff, NB);
        k_rowptr<<<NB, blk, 0, stream>>>(cnt, boff, rowptr);
        k_scatter<<<1024, blk, 0, stream>>>((const int4*)rows, (const int4*)cols,
                                            (const float4*)vals, (const int4*)rank,
                                            rowptr, cnt8, scv);

        // ---- 3 gather layers (bf16 gathers), fused output accumulation ----
        k_spmm_csr<1><<<NNODES / 4, blk, 0, stream>>>(rowptr, scv, x0b,
                                                      (const float4*)groups, x1b,
                                                      (float4*)out);
        k_spmm_csr<2><<<NNODES / 4, blk, 0, stream>>>(rowptr, scv, x1b,
                                                      (const float4*)groups, x2b,
                                                      (float4*)out);
        k_spmm_csr<3><<<NGROUPS / 4, blk, 0, stream>>>(rowptr, scv, x2b,
                                                       (const float4*)groups, nullptr,
                                                       (float4*)out);
    } else {
        // ---- fallback: proven atomic-scatter path (f32) ----
        float* xA = x1;
        float* xB = x2;
        k_concat<<<2048, blk, 0, stream>>>((const float4*)groups, (const float4*)items,
                                           (float4*)xA);
        for (int l = 0; l < 3; ++l) {
            k_zero<<<2048, blk, 0, stream>>>((float4*)xB, NNODES * DIM / 4);
            k_spmm<<<4096, blk, 0, stream>>>(rows, cols, vals, xA, xB);
            k_accum<<<512, blk, 0, stream>>>((const float4*)xB, (float4*)out, l == 0);
            float* t = xA; xA = xB; xB = t;
        }
        k_final<<<512, blk, 0, stream>>>((const float4*)groups, (float4*)out);
    }
}